// Round 13
// baseline (147.779 us; speedup 1.0000x reference)
//
#include <hip/hip_runtime.h>

#define NBATCH 4096
#define SEQ 512
#define HID 5
#define NEMB 64

__device__ __forceinline__ float fexp2(float x){ return __builtin_amdgcn_exp2f(x); }
__device__ __forceinline__ float frcp(float x){ return __builtin_amdgcn_rcpf(x); }

// quad_perm broadcast of quad-lane j to the whole quad (bound_ctrl=1)
#define DPPQ(v, j) __int_as_float(__builtin_amdgcn_update_dpp(0, __float_as_int(v), ((j) * 0x55), 0xF, 0xF, true))
// zero-fill DPP permute (bound_ctrl=1, no merge, no hazard-prone old-value dep)
#define DPPZ(v, CTRL) __int_as_float(__builtin_amdgcn_update_dpp(0, __float_as_int(v), (CTRL), 0xF, 0xF, true))
// rotations within each 16-lane row (r10-verified): shl-k zero-fill + shr-(16-k) zero-fill
#define ROT4(v)  (DPPZ(v, 0x104) + DPPZ(v, 0x11C))   /* h[(l+4)  & 15] */
#define ROT8(v)  (DPPZ(v, 0x128))                    /* h[(l+8)  & 15] (row_ror:8) */
#define ROT12(v) (DPPZ(v, 0x10C) + DPPZ(v, 0x114))   /* h[(l+12) & 15] */

__global__ __launch_bounds__(64) void lstm_enc_kernel(
    const float* __restrict__ x_num, const int* __restrict__ x_cat,
    const float* __restrict__ embed, const float* __restrict__ W_ih,
    const float* __restrict__ W_hh, const float* __restrict__ b_ih,
    const float* __restrict__ b_hh, float* __restrict__ out)
{
    __shared__ float4 s_emb[NEMB];
    int tid = threadIdx.x;
    s_emb[tid] = ((const float4*)embed)[tid];
    __syncthreads();

    // element = 16-lane DPP row; 2 elements per wave (lanes 0-15, 16-31);
    // lanes 32-63 duplicate them (same b, stores masked) to keep W=2/SIMD.
    // lane l in row: quad q=l>>2 owns unit q; unit 4 rides as 2nd scalar on all lanes.
    int l    = tid & 15;
    int q    = l >> 2;
    int g    = l & 3;                   // 0:i 1:f 2:g 3:o
    int elem = (tid >> 4) & 1;
    int b    = blockIdx.x * 2 + elem;
    bool act_lane = (tid < 32);

    bool st  = act_lane && ((g == 0) || (l == 1)); // units 0-3 from g==0 lanes; unit 4 from lane 1
    bool is4 = (l == 1);
    int  col = is4 ? 4 : q;

    const float L2E = 1.4426950408889634f;
    const float CS  = -2.0f * L2E;
    float s_  = (g == 2) ? CS : -L2E;   // prescale: tanh gate -2log2e, sigmoid -log2e
    float fm  = (g == 2) ? 2.0f : 1.0f; // activation fixup v = r*fm+fb
    float fb  = (g == 2) ? -1.0f : 0.0f;

    int rowO = g * HID + q;             // own-unit gate row
    int row4 = g * HID + 4;             // unit-4 gate row
    float wiO[5], wi4[5], wrO[5], wr4[5];
#pragma unroll
    for (int d = 0; d < 5; ++d) {
        wiO[d] = W_ih[rowO * 5 + d] * s_;
        wi4[d] = W_ih[row4 * 5 + d] * s_;
    }
#pragma unroll
    for (int r = 0; r < 4; ++r) {       // h-weights pre-permuted for rotate-dot
        int idx = (q + r) & 3;
        wrO[r] = W_hh[rowO * 5 + idx] * s_;
        wr4[r] = W_hh[row4 * 5 + idx] * s_;
    }
    wrO[4] = W_hh[rowO * 5 + 4] * s_;
    wr4[4] = W_hh[row4 * 5 + 4] * s_;
    float biasO = (b_ih[rowO] + b_hh[rowO]) * s_;
    float bias4 = (b_ih[row4] + b_hh[row4]) * s_;

    const float4* xp = (const float4*)(x_num + (size_t)b * SEQ);
    const int4*   cp = (const int4*)(x_cat + (size_t)b * SEQ);
    float* outp = out + (size_t)b * SEQ * HID;

    float hq = 0.f, cq = 0.f, h4 = 0.f, c4 = 0.f;
    float t4 = 0.f, t8 = 0.f, t12 = 0.f;   // rotations of hq, computed at step end

    // depth-2 prefetch of x/cat; emb staged one block ahead
    float4 xf_c = xp[0];  int4 cf_c = cp[0];
    float4 xf_1 = xp[1];  int4 cf_1 = cp[1];
    float4 ec_c[4];
    ec_c[0] = s_emb[cf_c.x]; ec_c[1] = s_emb[cf_c.y];
    ec_c[2] = s_emb[cf_c.z]; ec_c[3] = s_emb[cf_c.w];

    for (int t0 = 0; t0 < SEQ; t0 += 4) {
        int n2 = (t0 >> 2) + 2;
        if (n2 > (SEQ / 4 - 1)) n2 = SEQ / 4 - 1;
        float4 xf_2 = xp[n2];
        int4   cf_2 = cp[n2];

        // next block's emb rows (cf_1 long-landed)
        float4 ec_n0 = s_emb[cf_1.x];
        float4 ec_n1 = s_emb[cf_1.y];
        float4 ec_n2 = s_emb[cf_1.z];
        float4 ec_n3 = s_emb[cf_1.w];

        float xn_a[4] = {xf_c.x, xf_c.y, xf_c.z, xf_c.w};

        // off-chain: bias + x + emb for both components, 4 steps
        float xaO[4], xa4[4];
#pragma unroll
        for (int u = 0; u < 4; ++u) {
            float4 e = ec_c[u];
            float aO  = fmaf(xn_a[u], wiO[0], biasO);
            float a4v = fmaf(xn_a[u], wi4[0], bias4);
            aO  = fmaf(e.x, wiO[1], aO);   a4v = fmaf(e.x, wi4[1], a4v);
            aO  = fmaf(e.y, wiO[2], aO);   a4v = fmaf(e.y, wi4[2], a4v);
            aO  = fmaf(e.z, wiO[3], aO);   a4v = fmaf(e.z, wi4[3], a4v);
            aO  = fmaf(e.w, wiO[4], aO);   a4v = fmaf(e.w, wi4[4], a4v);
            xaO[u] = aO; xa4[u] = a4v;
        }

#pragma unroll
        for (int u = 0; u < 4; ++u) {
            // rotate-dot: rotations t4/t8/t12 were computed at the end of the
            // previous step — the dot starts with ZERO cross-lane wait.
            float aO = xaO[u], a4v = xa4[u];
            aO = fmaf(h4,  wrO[4], aO);   a4v = fmaf(h4,  wr4[4], a4v);
            aO = fmaf(hq,  wrO[0], aO);   a4v = fmaf(hq,  wr4[0], a4v);
            aO = fmaf(t4,  wrO[1], aO);   a4v = fmaf(t4,  wr4[1], a4v);
            aO = fmaf(t8,  wrO[2], aO);   a4v = fmaf(t8,  wr4[2], a4v);
            aO = fmaf(t12, wrO[3], aO);   a4v = fmaf(t12, wr4[3], a4v);

            // one sigma per component; tanh-gate lanes fix up 2r-1
            float rO = frcp(1.0f + fexp2(aO));
            float r4 = frcp(1.0f + fexp2(a4v));
            float vO = fmaf(rO, fm, fb);
            float v4 = fmaf(r4, fm, fb);

            // gather i,f,g,o within the quad for both components
            float aiO = DPPQ(vO, 0), afO = DPPQ(vO, 1), agO = DPPQ(vO, 2), aoO = DPPQ(vO, 3);
            float ai4 = DPPQ(v4, 0), af4 = DPPQ(v4, 1), ag4 = DPPQ(v4, 2), ao4 = DPPQ(v4, 3);

            cq = fmaf(afO, cq, aiO * agO);
            c4 = fmaf(af4, c4, ai4 * ag4);

            float tO  = frcp(1.0f + fexp2(cq * CS));
            float t4c = frcp(1.0f + fexp2(c4 * CS));
            hq = fmaf(tO,  aoO + aoO, -aoO);   // o * (2*sigma(2c)-1)
            h4 = fmaf(t4c, ao4 + ao4, -ao4);

            // rotations for the NEXT step, issued immediately (cheap VALU DPP)
            t4  = ROT4(hq);
            t8  = ROT8(hq);
            t12 = ROT12(hq);

            if (st) outp[(t0 + u) * HID + col] = is4 ? h4 : hq;
        }

        ec_c[0] = ec_n0; ec_c[1] = ec_n1; ec_c[2] = ec_n2; ec_c[3] = ec_n3;
        xf_c = xf_1; xf_1 = xf_2;
        cf_c = cf_1; cf_1 = cf_2;
    }

    if (st) {
        size_t base = (size_t)NBATCH * SEQ * HID;
        out[base + (size_t)b * HID + col] = is4 ? h4 : hq;                          // hT
        out[base + (size_t)NBATCH * HID + (size_t)b * HID + col] = is4 ? c4 : cq;   // cT
    }
}

extern "C" void kernel_launch(void* const* d_in, const int* in_sizes, int n_in,
                              void* d_out, int out_size, void* d_ws, size_t ws_size,
                              hipStream_t stream) {
    const float* x_num = (const float*)d_in[0];
    const int*   x_cat = (const int*)d_in[1];
    const float* embed = (const float*)d_in[2];
    const float* W_ih  = (const float*)d_in[3];
    const float* W_hh  = (const float*)d_in[4];
    const float* b_ih  = (const float*)d_in[5];
    const float* b_hh  = (const float*)d_in[6];
    float* out = (float*)d_out;

    dim3 grid(NBATCH / 2);   // 2048 blocks, 1 wave each: 2 elements/wave -> 2 waves/SIMD
    dim3 block(64);
    hipLaunchKernelGGL(lstm_enc_kernel, grid, block, 0, stream,
                       x_num, x_cat, embed, W_ih, W_hh, b_ih, b_hh, out);
}

// Round 14
// 115.957 us; speedup vs baseline: 1.2744x; 1.2744x over previous
//
#include <hip/hip_runtime.h>

#define NBATCH 4096
#define SEQ 512
#define HID 5
#define NEMB 64

__device__ __forceinline__ float frcp(float x){ return __builtin_amdgcn_rcpf(x); }

// Pade [5/4] tanh, clamped to +-3.5; max err ~1.5e-3; one rcp, no exp2 (r12-validated)
__device__ __forceinline__ float pade_tanh(float y) {
    y = fminf(fmaxf(y, -3.5f), 3.5f);
    float z = y * y;
    float n = y * fmaf(z, z + 105.0f, 945.0f);          // y*(z^2+105z+945)
    float d = fmaf(z, fmaf(z, 15.0f, 420.0f), 945.0f);  // 15z^2+420z+945
    return n * frcp(d);
}

// quad_perm broadcast of quad-lane j to the whole quad (bound_ctrl=1)
#define DPPQ(v, j) __int_as_float(__builtin_amdgcn_update_dpp(0, __float_as_int(v), ((j) * 0x55), 0xF, 0xF, true))
// zero-fill DPP permute (bound_ctrl=1, no merge -> no read-modify hazard)
#define DPPZ(v, CTRL) __int_as_float(__builtin_amdgcn_update_dpp(0, __float_as_int(v), (CTRL), 0xF, 0xF, true))
// rotations within each 16-lane row (r10-verified on HW)
#define ROT4(v)  (DPPZ(v, 0x104) + DPPZ(v, 0x11C))   /* h[(l+4)  & 15] */
#define ROT8(v)  (DPPZ(v, 0x128))                    /* h[(l+8)  & 15] (row_ror:8) */
#define ROT12(v) (DPPZ(v, 0x10C) + DPPZ(v, 0x114))   /* h[(l+12) & 15] */

__global__ __launch_bounds__(64) void lstm_enc_kernel(
    const float* __restrict__ x_num, const int* __restrict__ x_cat,
    const float* __restrict__ embed, const float* __restrict__ W_ih,
    const float* __restrict__ W_hh, const float* __restrict__ b_ih,
    const float* __restrict__ b_hh, float* __restrict__ out)
{
    int tid = threadIdx.x;
    // element = 16-lane DPP row, 4 elements per wave, 1 wave per SIMD (1024 blocks).
    // lane l in row: quad q=l>>2 owns unit q (comp O); unit 4 rides as 2nd scalar
    // on all lanes (comp 4). g=l&3 is the gate (0:i 1:f 2:g 3:o).
    int grp = tid >> 4;
    int l   = tid & 15;
    int q   = l >> 2;
    int g   = l & 3;
    int b   = blockIdx.x * 4 + grp;

    bool st  = (g == 0) || (l == 1);    // storing lanes: q-holders + lane1 for unit 4
    bool is4 = (l == 1);
    int  col = is4 ? 4 : q;

    // sigmoid gates (g!=2): sigma(x)=0.5+0.5*tanh(x/2) -> prescale 0.5
    // tanh gate  (g==2): tanh(x) direct -> prescale 1.0
    float s_  = (g == 2) ? 1.0f : 0.5f;
    float fm  = (g == 2) ? 1.0f : 0.5f;     // v = t*fm + fb
    float fb  = (g == 2) ? 0.0f : 0.5f;

    int rowO = g * HID + q;
    int row4 = g * HID + 4;
    float wiO[5], wi4[5], wrO[5], wr4[5];
#pragma unroll
    for (int d = 0; d < 5; ++d) {
        wiO[d] = W_ih[rowO * 5 + d] * s_;
        wi4[d] = W_ih[row4 * 5 + d] * s_;
    }
#pragma unroll
    for (int r = 0; r < 4; ++r) {           // h-weights pre-permuted for rotate-dot
        int idx = (q + r) & 3;
        wrO[r] = W_hh[rowO * 5 + idx] * s_;
        wr4[r] = W_hh[row4 * 5 + idx] * s_;
    }
    wrO[4] = W_hh[rowO * 5 + 4] * s_;
    wr4[4] = W_hh[row4 * 5 + 4] * s_;
    float biasO = (b_ih[rowO] + b_hh[rowO]) * s_;
    float bias4 = (b_ih[row4] + b_hh[row4]) * s_;

    const float4* xp = (const float4*)(x_num + (size_t)b * SEQ);
    const int4*   cp = (const int4*)(x_cat + (size_t)b * SEQ);
    const float4* ep = (const float4*)embed;     // 1 KB table, L1-resident
    float* outp = out + (size_t)b * SEQ * HID;

    float hq = 0.f, cq = 0.f, h4 = 0.f, c4 = 0.f;
    float t4 = 0.f, t8 = 0.f, t12 = 0.f;         // rotations of hq (step-end issued)

    // depth-2 prefetch of x/cat; emb rows loaded one block ahead (global/L1)
    float4 xf_c = xp[0];  int4 cf_c = cp[0];
    float4 xf_1 = xp[1];  int4 cf_1 = cp[1];
    float4 ec_c[4];
    ec_c[0] = ep[cf_c.x]; ec_c[1] = ep[cf_c.y];
    ec_c[2] = ep[cf_c.z]; ec_c[3] = ep[cf_c.w];

    // prologue: xa for t=0
    float xaO_cur, xa4_cur;
    {
        float4 e = ec_c[0];
        float aO  = fmaf(xf_c.x, wiO[0], biasO);
        float a4v = fmaf(xf_c.x, wi4[0], bias4);
        aO  = fmaf(e.x, wiO[1], aO);   a4v = fmaf(e.x, wi4[1], a4v);
        aO  = fmaf(e.y, wiO[2], aO);   a4v = fmaf(e.y, wi4[2], a4v);
        aO  = fmaf(e.z, wiO[3], aO);   a4v = fmaf(e.z, wi4[3], a4v);
        aO  = fmaf(e.w, wiO[4], aO);   a4v = fmaf(e.w, wi4[4], a4v);
        xaO_cur = aO; xa4_cur = a4v;
    }

    for (int t0 = 0; t0 < SEQ; t0 += 4) {
        int n2 = (t0 >> 2) + 2;
        if (n2 > (SEQ / 4 - 1)) n2 = SEQ / 4 - 1;
        float4 xf_2 = xp[n2];
        int4   cf_2 = cp[n2];

        // next block's emb rows from global (cf_1 long-landed; L1 hit)
        float4 ec_n0 = ep[cf_1.x];
        float4 ec_n1 = ep[cf_1.y];
        float4 ec_n2 = ep[cf_1.z];
        float4 ec_n3 = ep[cf_1.w];

        float xn_a[4] = {xf_c.x, xf_c.y, xf_c.z, xf_c.w};

#pragma unroll
        for (int u = 0; u < 4; ++u) {
            // ---- recurrent chain (rotations t4/t8/t12 ready from last step) ----
            float aO = xaO_cur, a4v = xa4_cur;
            aO = fmaf(h4,  wrO[4], aO);   a4v = fmaf(h4,  wr4[4], a4v);
            aO = fmaf(hq,  wrO[0], aO);   a4v = fmaf(hq,  wr4[0], a4v);
            aO = fmaf(t4,  wrO[1], aO);   a4v = fmaf(t4,  wr4[1], a4v);
            aO = fmaf(t8,  wrO[2], aO);   a4v = fmaf(t8,  wr4[2], a4v);
            aO = fmaf(t12, wrO[3], aO);   a4v = fmaf(t12, wr4[3], a4v);

            // one Pade per component; sigma-gates fix up 0.5+0.5t
            float tO = pade_tanh(aO);
            float tf4 = pade_tanh(a4v);
            float vO = fmaf(tO,  fm, fb);
            float v4 = fmaf(tf4, fm, fb);

            // gather i,f,g,o within the quad for both components
            float aiO = DPPQ(vO, 0), afO = DPPQ(vO, 1), agO = DPPQ(vO, 2), aoO = DPPQ(vO, 3);
            float ai4 = DPPQ(v4, 0), af4 = DPPQ(v4, 1), ag4 = DPPQ(v4, 2), ao4 = DPPQ(v4, 3);

            cq = fmaf(afO, cq, aiO * agO);
            c4 = fmaf(af4, c4, ai4 * ag4);

            float hn  = aoO * pade_tanh(cq);
            float hn4 = ao4 * pade_tanh(c4);
            hq = hn; h4 = hn4;

            // rotations for the NEXT step, issued immediately
            t4  = ROT4(hq);
            t8  = ROT8(hq);
            t12 = ROT12(hq);

            // ---- filler: xa for step t+1 (independent of the chain tail) ----
            {
                float xn_nxt = (u < 3) ? xn_a[u + 1] : xf_1.x;
                float4 e     = (u < 3) ? ec_c[u + 1] : ec_n0;
                float aO2  = fmaf(xn_nxt, wiO[0], biasO);
                float a4v2 = fmaf(xn_nxt, wi4[0], bias4);
                aO2  = fmaf(e.x, wiO[1], aO2);   a4v2 = fmaf(e.x, wi4[1], a4v2);
                aO2  = fmaf(e.y, wiO[2], aO2);   a4v2 = fmaf(e.y, wi4[2], a4v2);
                aO2  = fmaf(e.z, wiO[3], aO2);   a4v2 = fmaf(e.z, wi4[3], a4v2);
                aO2  = fmaf(e.w, wiO[4], aO2);   a4v2 = fmaf(e.w, wi4[4], a4v2);
                xaO_cur = aO2; xa4_cur = a4v2;
            }
            if (st) outp[(t0 + u) * HID + col] = is4 ? h4 : hq;
        }

        ec_c[0] = ec_n0; ec_c[1] = ec_n1; ec_c[2] = ec_n2; ec_c[3] = ec_n3;
        xf_c = xf_1; xf_1 = xf_2;
        cf_c = cf_1; cf_1 = cf_2;
    }

    if (st) {
        size_t base = (size_t)NBATCH * SEQ * HID;
        out[base + (size_t)b * HID + col] = is4 ? h4 : hq;                          // hT
        out[base + (size_t)NBATCH * HID + (size_t)b * HID + col] = is4 ? c4 : cq;   // cT
    }
}

extern "C" void kernel_launch(void* const* d_in, const int* in_sizes, int n_in,
                              void* d_out, int out_size, void* d_ws, size_t ws_size,
                              hipStream_t stream) {
    const float* x_num = (const float*)d_in[0];
    const int*   x_cat = (const int*)d_in[1];
    const float* embed = (const float*)d_in[2];
    const float* W_ih  = (const float*)d_in[3];
    const float* W_hh  = (const float*)d_in[4];
    const float* b_ih  = (const float*)d_in[5];
    const float* b_hh  = (const float*)d_in[6];
    float* out = (float*)d_out;

    dim3 grid(NBATCH / 4);   // 1024 blocks, 1 wave each: 4 elements/wave, 1 wave/SIMD
    dim3 block(64);
    hipLaunchKernelGGL(lstm_enc_kernel, grid, block, 0, stream,
                       x_num, x_cat, embed, W_ih, W_hh, b_ih, b_hh, out);
}